// Round 1
// 747.691 us; speedup vs baseline: 1.0937x; 1.0937x over previous
//
#include <hip/hip_runtime.h>
#include <hip/hip_bf16.h>
#include <math.h>

#define NS 100000
#define NR 100000
#define NE 600000
#define SILU_NORM 1.679177f

typedef __attribute__((ext_vector_type(8))) short short8;
typedef __attribute__((ext_vector_type(4))) float f32x4;

static __device__ __forceinline__ short f2bf(float f) {
    return __builtin_bit_cast(short, __float2bfloat16(f));
}

#define GLDS16(g, l)                                                         \
    __builtin_amdgcn_global_load_lds(                                        \
        (const __attribute__((address_space(1))) unsigned int*)(const void*)(g), \
        (__attribute__((address_space(3))) unsigned int*)(void*)(l), 16, 0, 0)

// ---------------------------------------------------------------------------
// Pre-swizzle a weight matrix W[K][128] (f32, k = u*8+v) into frag-major bf16:
// flat = s*4096 + f*512 + quad*128 + wl*8 + j  <-  W[(s*32+quad*8+j)*128 + f*16+wl]
// so a B-fragment (16x16x32: lane holds B[k=quad*8+j][w=f*16+(lane&15)]) is a
// lane-contiguous 16B load at (f*64+lane)*16B within kstep chunk s.
// ---------------------------------------------------------------------------
__global__ void swz_kernel(const float* __restrict__ W,
                           __hip_bfloat16* __restrict__ out, int total)
{
    int idx = blockIdx.x * 256 + threadIdx.x;
    if (idx >= total) return;
    int s = idx >> 12, r = idx & 4095;
    int f = r >> 9;  r &= 511;
    int quad = r >> 7; r &= 127;
    int wl = r >> 3;
    int j = r & 7;
    int k = s * 32 + quad * 8 + j;
    int w = f * 16 + wl;
    out[idx] = __float2bfloat16(W[(size_t)k * 128 + w]);
}

// ---------------------------------------------------------------------------
// fctp via MFMA: out[n,w] = scale * sum_k A[n,k]*W[k,w], A[n,u*8+v]=x[n,u]*y[n,v]
// A-frag trick: lane (m=lane&15) holds A[m][quad*8 + 0..7] = x[m][u]*y[m][0..7]
// Block: 256 thr, 4 waves, 32 nodes/wave (2 m-tiles), 128 nodes/block.
// ---------------------------------------------------------------------------
__global__ __launch_bounds__(256) void fctp_mfma_kernel(
    const float* __restrict__ x, const float* __restrict__ y,
    const __hip_bfloat16* __restrict__ Wswz, float* __restrict__ out,
    float scale, int N)
{
    __shared__ __hip_bfloat16 Wb[8192];  // 16 KB: K=64 chunk (2 ksteps x 4096)
    __shared__ float xs[128 * 8];        // 4 KB: x[nodeLocal][c], u = cc*8+c

    const int tid = threadIdx.x;
    const int lane = tid & 63;
    const int wv = tid >> 6;
    const int quad = lane >> 4;
    const int wl = lane & 15;
    const int n0 = blockIdx.x * 128;

    float ya[2][8];
    #pragma unroll
    for (int mt = 0; mt < 2; ++mt) {
        int node = n0 + wv * 32 + mt * 16 + wl;
        if (node >= N) node = N - 1;
        const float4* yp = (const float4*)(y + (size_t)node * 8);
        float4 a = yp[0], b = yp[1];
        ya[mt][0] = a.x; ya[mt][1] = a.y; ya[mt][2] = a.z; ya[mt][3] = a.w;
        ya[mt][4] = b.x; ya[mt][5] = b.y; ya[mt][6] = b.z; ya[mt][7] = b.w;
    }

    f32x4 acc[2][8];
    #pragma unroll
    for (int mt = 0; mt < 2; ++mt)
        #pragma unroll
        for (int f = 0; f < 8; ++f)
            acc[mt][f] = (f32x4){0.f, 0.f, 0.f, 0.f};

    for (int cc = 0; cc < 16; ++cc) {          // K chunks of 64
        __syncthreads();
        {
            const char* src = (const char*)(Wswz + (size_t)cc * 8192);
            #pragma unroll
            for (int i = 0; i < 4; ++i) {
                int off = (i * 256 + tid) * 16;
                GLDS16(src + off, (char*)Wb + off);
            }
            int nl = tid >> 1, c4 = (tid & 1) * 4;
            int node = n0 + nl;
            if (node >= N) node = N - 1;
            GLDS16(x + (size_t)node * 128 + cc * 8 + c4, (char*)xs + tid * 16);
        }
        __syncthreads();

        #pragma unroll
        for (int ks = 0; ks < 2; ++ks) {
            short8 bfr[8];
            #pragma unroll
            for (int f = 0; f < 8; ++f)
                bfr[f] = *(const short8*)((const short*)Wb +
                                          (size_t)ks * 4096 + (f * 64 + lane) * 8);
            #pragma unroll
            for (int mt = 0; mt < 2; ++mt) {
                float xv = xs[(wv * 32 + mt * 16 + wl) * 8 + ks * 4 + quad];
                short8 af;
                #pragma unroll
                for (int v = 0; v < 8; ++v) af[v] = f2bf(xv * ya[mt][v]);
                #pragma unroll
                for (int f = 0; f < 8; ++f)
                    acc[mt][f] = __builtin_amdgcn_mfma_f32_16x16x32_bf16(
                        af, bfr[f], acc[mt][f], 0, 0, 0);
            }
        }
    }

    #pragma unroll
    for (int mt = 0; mt < 2; ++mt) {
        #pragma unroll
        for (int r = 0; r < 4; ++r) {
            int node = n0 + wv * 32 + mt * 16 + quad * 4 + r;
            if (node < N) {
                #pragma unroll
                for (int f = 0; f < 8; ++f)
                    out[(size_t)node * 128 + f * 16 + wl] = acc[mt][f][r] * scale;
            }
        }
    }
}

// ---------------------------------------------------------------------------
// Edge kernel, occupancy-first restructure:
//  - fc1 A-frags loaded DIRECT from escal (32B/lane, coalesced 128B row chunks,
//    each byte read exactly once) -> no esA staging.
//  - fc1/fc2 B-frags loaded DIRECT from swizzled weights (lane-contiguous 1KB
//    per wave-load, 48KB total, L1/L2-hot across all blocks) -> no Wb staging.
//  - only hA (fc1->fc2 per-wave transpose, 32 KB) stays in LDS.
//  LDS 80KB -> 32KB: 5 blocks/CU vs 2; one barrier instead of four.
// ---------------------------------------------------------------------------
__global__ __launch_bounds__(256, 4) void edge_mfma_kernel(
    const int* __restrict__ esrc, const int* __restrict__ edst,
    const float* __restrict__ eattr, const float* __restrict__ escal,
    const __hip_bfloat16* __restrict__ W1swz,   // 8192  shorts (K=64 swizzled)
    const __hip_bfloat16* __restrict__ W2swz,   // 16384 shorts (K=128 swizzled)
    const float* __restrict__ sf, float* __restrict__ rfeat)
{
    __shared__ __hip_bfloat16 hA[16384];   // 32 KB  A-frag-major hidden (per-wave 8KB)

    const int tid = threadIdx.x;
    const int lane = tid & 63;
    const int wv = tid >> 6;
    const int quad = lane >> 4;
    const int wl = lane & 15;
    const int e0 = blockIdx.x * 128;

    // ---- fc1: [128 x 64] @ [64 x 128] ----
    // A-frag direct: lane holds es[e0+MT*16+wl][ks*32 + quad*8 .. +8]
    short8 af1[2][2];
    #pragma unroll
    for (int ks = 0; ks < 2; ++ks)
        #pragma unroll
        for (int mt = 0; mt < 2; ++mt) {
            int e = e0 + (wv * 2 + mt) * 16 + wl;
            if (e >= NE) e = NE - 1;
            const float4* p = (const float4*)(escal + (size_t)e * 64 + ks * 32 + quad * 8);
            float4 a = p[0], b = p[1];
            short8 v;
            v[0] = f2bf(a.x); v[1] = f2bf(a.y); v[2] = f2bf(a.z); v[3] = f2bf(a.w);
            v[4] = f2bf(b.x); v[5] = f2bf(b.y); v[6] = f2bf(b.z); v[7] = f2bf(b.w);
            af1[ks][mt] = v;
        }

    f32x4 acc1[2][8];
    #pragma unroll
    for (int mt = 0; mt < 2; ++mt)
        #pragma unroll
        for (int f = 0; f < 8; ++f) acc1[mt][f] = (f32x4){0.f, 0.f, 0.f, 0.f};

    #pragma unroll
    for (int ks = 0; ks < 2; ++ks)
        #pragma unroll
        for (int f = 0; f < 8; ++f) {
            short8 bfr = *(const short8*)((const short*)W1swz +
                                          (size_t)ks * 4096 + (f * 64 + lane) * 8);
            acc1[0][f] = __builtin_amdgcn_mfma_f32_16x16x32_bf16(
                af1[ks][0], bfr, acc1[0][f], 0, 0, 0);
            acc1[1][f] = __builtin_amdgcn_mfma_f32_16x16x32_bf16(
                af1[ks][1], bfr, acc1[1][f], 0, 0, 0);
        }

    // silu + write h to hA in fc2 A-frag order (per-wave region, scatter u16)
    #pragma unroll
    for (int mt = 0; mt < 2; ++mt) {
        int MT = wv * 2 + mt;
        #pragma unroll
        for (int f = 0; f < 8; ++f) {
            int s2 = f >> 1;
            int q2 = ((f & 1) * 2 + (wl >> 3)) & 3;
            int j2 = wl & 7;
            #pragma unroll
            for (int r = 0; r < 4; ++r) {
                float t = acc1[mt][f][r] * 0.125f;              // 1/sqrt(64)
                float h = SILU_NORM * t / (1.f + __expf(-t));
                int lpos = q2 * 16 + quad * 4 + r;
                ((short*)hA)[((size_t)(s2 * 8 + MT) * 64 + lpos) * 8 + j2] = f2bf(h);
            }
        }
    }
    __syncthreads();   // cross-lane hA visibility (cheap: only barrier in kernel)

    // ---- fc2: [128 x 128] @ [128 x 128] ----
    f32x4 acc2[2][8];
    #pragma unroll
    for (int mt = 0; mt < 2; ++mt)
        #pragma unroll
        for (int f = 0; f < 8; ++f) acc2[mt][f] = (f32x4){0.f, 0.f, 0.f, 0.f};

    #pragma unroll
    for (int ks = 0; ks < 4; ++ks) {
        short8 afA = *(const short8*)((const short*)hA +
                                      ((size_t)(ks * 8 + wv * 2 + 0) * 64 + lane) * 8);
        short8 afB = *(const short8*)((const short*)hA +
                                      ((size_t)(ks * 8 + wv * 2 + 1) * 64 + lane) * 8);
        #pragma unroll
        for (int f = 0; f < 8; ++f) {
            short8 bfr = *(const short8*)((const short*)W2swz +
                                          (size_t)ks * 4096 + (f * 64 + lane) * 8);
            acc2[0][f] = __builtin_amdgcn_mfma_f32_16x16x32_bf16(
                afA, bfr, acc2[0][f], 0, 0, 0);
            acc2[1][f] = __builtin_amdgcn_mfma_f32_16x16x32_bf16(
                afB, bfr, acc2[1][f], 0, 0, 0);
        }
    }

    // epilogue: wt * eattr' * sf[src] -> atomicAdd rfeat[dst]
    const float s128 = 0.08838834764831845f;   // 1/sqrt(128)
    #pragma unroll
    for (int mt = 0; mt < 2; ++mt) {
        int MT = wv * 2 + mt;
        #pragma unroll
        for (int r = 0; r < 4; ++r) {
            int e = e0 + MT * 16 + quad * 4 + r;
            if (e < NE) {
                int src = esrc[e], dst = edst[e];
                float ea = eattr[e] * s128;
                #pragma unroll
                for (int f = 0; f < 8; ++f) {
                    float val = acc2[mt][f][r] * ea *
                                sf[(size_t)src * 128 + f * 16 + wl];
                    atomicAdd(&rfeat[(size_t)dst * 128 + f * 16 + wl], val);
                }
            }
        }
    }
}

// ---------------------------------------------------------------------------
// Fused tail: conv = fctp(rfeat, rattr, W_lin2), angle = 0.1*fctp(rfeat, rattr,
// W_lin3) computed from the SAME f32 A-products, then out = cos(a)*rsc +
// sin(a)*conv written inline. Removes conv/angle round-trips + 2 launches.
// ---------------------------------------------------------------------------
__global__ __launch_bounds__(256) void conv_fuse_kernel(
    const float* __restrict__ x, const float* __restrict__ y,
    const __hip_bfloat16* __restrict__ Wswz, const float* __restrict__ W3,
    const float* __restrict__ rsc, float* __restrict__ out, int N)
{
    __shared__ __hip_bfloat16 Wb[8192];  // 16 KB
    __shared__ float xs[128 * 8];        // 4 KB

    const int tid = threadIdx.x;
    const int lane = tid & 63;
    const int wv = tid >> 6;
    const int quad = lane >> 4;
    const int wl = lane & 15;
    const int n0 = blockIdx.x * 128;

    float ya[2][8];
    #pragma unroll
    for (int mt = 0; mt < 2; ++mt) {
        int node = n0 + wv * 32 + mt * 16 + wl;
        if (node >= N) node = N - 1;
        const float4* yp = (const float4*)(y + (size_t)node * 8);
        float4 a = yp[0], b = yp[1];
        ya[mt][0] = a.x; ya[mt][1] = a.y; ya[mt][2] = a.z; ya[mt][3] = a.w;
        ya[mt][4] = b.x; ya[mt][5] = b.y; ya[mt][6] = b.z; ya[mt][7] = b.w;
    }

    f32x4 acc[2][8];
    #pragma unroll
    for (int mt = 0; mt < 2; ++mt)
        #pragma unroll
        for (int f = 0; f < 8; ++f)
            acc[mt][f] = (f32x4){0.f, 0.f, 0.f, 0.f};
    float aacc[2] = {0.f, 0.f};

    for (int cc = 0; cc < 16; ++cc) {
        __syncthreads();
        {
            const char* src = (const char*)(Wswz + (size_t)cc * 8192);
            #pragma unroll
            for (int i = 0; i < 4; ++i) {
                int off = (i * 256 + tid) * 16;
                GLDS16(src + off, (char*)Wb + off);
            }
            int nl = tid >> 1, c4 = (tid & 1) * 4;
            int node = n0 + nl;
            if (node >= N) node = N - 1;
            GLDS16(x + (size_t)node * 128 + cc * 8 + c4, (char*)xs + tid * 16);
        }
        __syncthreads();

        #pragma unroll
        for (int ks = 0; ks < 2; ++ks) {
            short8 bfr[8];
            #pragma unroll
            for (int f = 0; f < 8; ++f)
                bfr[f] = *(const short8*)((const short*)Wb +
                                          (size_t)ks * 4096 + (f * 64 + lane) * 8);
            // W3 row for u = cc*8 + ks*4 + quad (L1-hot 4KB table)
            const float4* wp = (const float4*)(W3 + ((cc * 8 + ks * 4 + quad) * 8));
            float4 w3a = wp[0], w3b = wp[1];
            float w3v[8] = {w3a.x, w3a.y, w3a.z, w3a.w, w3b.x, w3b.y, w3b.z, w3b.w};
            #pragma unroll
            for (int mt = 0; mt < 2; ++mt) {
                float xv = xs[(wv * 32 + mt * 16 + wl) * 8 + ks * 4 + quad];
                short8 af;
                #pragma unroll
                for (int v = 0; v < 8; ++v) {
                    float p = xv * ya[mt][v];
                    af[v] = f2bf(p);
                    aacc[mt] += p * w3v[v];
                }
                #pragma unroll
                for (int f = 0; f < 8; ++f)
                    acc[mt][f] = __builtin_amdgcn_mfma_f32_16x16x32_bf16(
                        af, bfr[f], acc[mt][f], 0, 0, 0);
            }
        }
    }

    // angle: reduce partials across the 4 quad-lanes sharing each node (m=wl)
    float ared[2];
    #pragma unroll
    for (int mt = 0; mt < 2; ++mt) {
        float a = aacc[mt];
        a += __shfl_xor(a, 16);
        a += __shfl_xor(a, 32);
        ared[mt] = a * 5.524271728019903e-4f;   // 0.1/(32*sqrt(32))
    }

    const float cs = 5.524271728019903e-3f;     // 1/(32*sqrt(32))
    #pragma unroll
    for (int mt = 0; mt < 2; ++mt) {
        #pragma unroll
        for (int r = 0; r < 4; ++r) {
            int node = n0 + wv * 32 + mt * 16 + quad * 4 + r;
            float a = __shfl(ared[mt], quad * 4 + r);   // lane with wl==quad*4+r
            if (node < N) {
                float ca = __cosf(a), sa = __sinf(a);
                #pragma unroll
                for (int f = 0; f < 8; ++f) {
                    size_t o = (size_t)node * 128 + f * 16 + wl;
                    out[o] = ca * rsc[o] + sa * (acc[mt][f][r] * cs);
                }
            }
        }
    }
}

// ---------------------------------------------------------------------------
extern "C" void kernel_launch(void* const* d_in, const int* in_sizes, int n_in,
                              void* d_out, int out_size, void* d_ws, size_t ws_size,
                              hipStream_t stream)
{
    const float* sender_input   = (const float*)d_in[0];
    const float* sender_attr    = (const float*)d_in[1];
    const float* receiver_input = (const float*)d_in[2];
    const float* receiver_attr  = (const float*)d_in[3];
    const int*   edge_src  = (const int*)d_in[4];
    const int*   edge_dst  = (const int*)d_in[5];
    const float* edge_attr = (const float*)d_in[6];
    const float* edge_scal = (const float*)d_in[7];
    const float* W_sc   = (const float*)d_in[8];
    const float* W_lin1 = (const float*)d_in[9];
    const float* W_fc1  = (const float*)d_in[10];
    const float* W_fc2  = (const float*)d_in[11];
    const float* W_lin2 = (const float*)d_in[12];
    const float* W_lin3 = (const float*)d_in[13];

    char* ws = (char*)d_ws;
    float* sf    = (float*)(ws);               // 51.2 MB ; reused as rsc after edge kernel
    float* rfeat = (float*)(ws + 51200000);    // 51.2 MB
    __hip_bfloat16* Wl1s = (__hip_bfloat16*)(ws + 102400000);  // 262144 B
    __hip_bfloat16* Wscs = (__hip_bfloat16*)(ws + 102662144);  // 262144 B
    __hip_bfloat16* Wl2s = (__hip_bfloat16*)(ws + 102924288);  // 262144 B
    __hip_bfloat16* W1s  = (__hip_bfloat16*)(ws + 103186432);  // 16384 B
    __hip_bfloat16* W2s  = (__hip_bfloat16*)(ws + 103202816);  // 32768 B
    float* rsc = sf;

    // weight pre-swizzles (one-time per launch, tiny)
    swz_kernel<<<512, 256, 0, stream>>>(W_lin1, Wl1s, 131072);
    swz_kernel<<<512, 256, 0, stream>>>(W_sc,   Wscs, 131072);
    swz_kernel<<<512, 256, 0, stream>>>(W_lin2, Wl2s, 131072);
    swz_kernel<<<32,  256, 0, stream>>>(W_fc1,  W1s,  8192);
    swz_kernel<<<64,  256, 0, stream>>>(W_fc2,  W2s,  16384);

    hipMemsetAsync(rfeat, 0, (size_t)NR * 128 * 4, stream);

    // sender_features = fctp(sender_input, sender_attr, W_lin1), scale 1/32
    fctp_mfma_kernel<<<(NS + 127) / 128, 256, 0, stream>>>(
        sender_input, sender_attr, Wl1s, sf, 0.03125f, NS);
    // edge FC + gather + scatter
    edge_mfma_kernel<<<(NE + 127) / 128, 256, 0, stream>>>(
        edge_src, edge_dst, edge_attr, edge_scal, W1s, W2s, sf, rfeat);
    // rsc = fctp(receiver_input, rattr, W_sc) * 1/32  (overwrites sf slot; edge
    // kernel has already consumed sf in stream order)
    fctp_mfma_kernel<<<(NR + 127) / 128, 256, 0, stream>>>(
        receiver_input, receiver_attr, Wscs, rsc, 0.03125f, NR);
    // fused conv + angle + trig combine -> out
    conv_fuse_kernel<<<(NR + 127) / 128, 256, 0, stream>>>(
        rfeat, receiver_attr, Wl2s, W_lin3, rsc, (float*)d_out, NR);
}

// Round 3
// 698.255 us; speedup vs baseline: 1.1712x; 1.0708x over previous
//
#include <hip/hip_runtime.h>
#include <hip/hip_bf16.h>
#include <math.h>

#define NS 100000
#define NR 100000
#define NE 600000
#define SILU_NORM 1.679177f

typedef __attribute__((ext_vector_type(8))) short short8;
typedef __attribute__((ext_vector_type(4))) float f32x4;

static __device__ __forceinline__ short f2bf(float f) {
    return __builtin_bit_cast(short, __float2bfloat16(f));
}

#define GLDS16(g, l)                                                         \
    __builtin_amdgcn_global_load_lds(                                        \
        (const __attribute__((address_space(1))) unsigned int*)(const void*)(g), \
        (__attribute__((address_space(3))) unsigned int*)(void*)(l), 16, 0, 0)

// ---------------------------------------------------------------------------
// Pre-swizzle a weight matrix W[K][128] (f32, k = u*8+v) into frag-major bf16:
// flat = s*4096 + f*512 + quad*128 + wl*8 + j  <-  W[(s*32+quad*8+j)*128 + f*16+wl]
// ---------------------------------------------------------------------------
__global__ void swz_kernel(const float* __restrict__ W,
                           __hip_bfloat16* __restrict__ out, int total)
{
    int idx = blockIdx.x * 256 + threadIdx.x;
    if (idx >= total) return;
    int s = idx >> 12, r = idx & 4095;
    int f = r >> 9;  r &= 511;
    int quad = r >> 7; r &= 127;
    int wl = r >> 3;
    int j = r & 7;
    int k = s * 32 + quad * 8 + j;
    int w = f * 16 + wl;
    out[idx] = __float2bfloat16(W[(size_t)k * 128 + w]);
}

// ---------------------------------------------------------------------------
// Counting sort of edges by dst: hist -> scan (3-pass) -> scatter.
// Buffers live in d_out (free until the final kernel overwrites it).
// ---------------------------------------------------------------------------
__global__ __launch_bounds__(256) void hist_kernel(const int* __restrict__ edst,
                                                   int* __restrict__ cnt)
{
    int i = blockIdx.x * 256 + threadIdx.x;
    if (i < NE) atomicAdd(&cnt[edst[i]], 1);
}

#define SCAN_BLK 1024   // elements per scan block (256 thr x 4)

__global__ __launch_bounds__(256) void scan1_kernel(const int* __restrict__ cnt,
                                                    int* __restrict__ bsum, int n)
{
    __shared__ int ts[256];
    int b = blockIdx.x, t = threadIdx.x;
    int base = b * SCAN_BLK + t * 4;
    int s = 0;
    #pragma unroll
    for (int k = 0; k < 4; ++k) { int i = base + k; if (i < n) s += cnt[i]; }
    ts[t] = s; __syncthreads();
    #pragma unroll
    for (int off = 128; off; off >>= 1) {
        if (t < off) ts[t] += ts[t + off];
        __syncthreads();
    }
    if (t == 0) bsum[b] = ts[0];
}

__global__ __launch_bounds__(128) void scan2_kernel(const int* __restrict__ bsum,
                                                    int* __restrict__ bofs, int nb)
{
    __shared__ int sh[128];
    int t = threadIdx.x;
    sh[t] = (t < nb) ? bsum[t] : 0;
    __syncthreads();
    for (int off = 1; off < 128; off <<= 1) {
        int v = (t >= off) ? sh[t - off] : 0;
        __syncthreads();
        sh[t] += v;
        __syncthreads();
    }
    if (t < nb) bofs[t] = (t == 0) ? 0 : sh[t - 1];
}

__global__ __launch_bounds__(256) void scan3_kernel(const int* __restrict__ cnt,
                                                    const int* __restrict__ bofs,
                                                    int* __restrict__ ofs, int n)
{
    __shared__ int ts[256];
    int b = blockIdx.x, t = threadIdx.x;
    int base = b * SCAN_BLK + t * 4;
    int v[4]; int s = 0;
    #pragma unroll
    for (int k = 0; k < 4; ++k) {
        int i = base + k;
        v[k] = (i < n) ? cnt[i] : 0;
        s += v[k];
    }
    ts[t] = s; __syncthreads();
    for (int off = 1; off < 256; off <<= 1) {
        int u = (t >= off) ? ts[t - off] : 0;
        __syncthreads();
        ts[t] += u;
        __syncthreads();
    }
    int run = bofs[b] + ts[t] - s;   // exclusive across threads
    #pragma unroll
    for (int k = 0; k < 4; ++k) {
        int i = base + k;
        if (i < n) ofs[i] = run;
        run += v[k];
    }
}

__global__ __launch_bounds__(256) void scatter_kernel(const int* __restrict__ edst,
                                                      int* __restrict__ ofs,
                                                      int* __restrict__ perm)
{
    int i = blockIdx.x * 256 + threadIdx.x;
    if (i < NE) {
        int pos = atomicAdd(&ofs[edst[i]], 1);
        perm[pos] = i;
    }
}

// ---------------------------------------------------------------------------
// fctp via MFMA, 2-phase double-buffered K-loop: STAGE(next) issued before
// compute(cur); single __syncthreads()/iter. Load latency hides under MFMA.
// ---------------------------------------------------------------------------
__global__ __launch_bounds__(256) void fctp_mfma_kernel(
    const float* __restrict__ x, const float* __restrict__ y,
    const __hip_bfloat16* __restrict__ Wswz, float* __restrict__ out,
    float scale, int N)
{
    __shared__ __hip_bfloat16 Wb[2][8192];  // 32 KB
    __shared__ float xs[2][128 * 8];        // 8 KB

    const int tid = threadIdx.x;
    const int lane = tid & 63;
    const int wv = tid >> 6;
    const int quad = lane >> 4;
    const int wl = lane & 15;
    const int n0 = blockIdx.x * 128;

    float ya[2][8];
    #pragma unroll
    for (int mt = 0; mt < 2; ++mt) {
        int node = n0 + wv * 32 + mt * 16 + wl;
        if (node >= N) node = N - 1;
        const float4* yp = (const float4*)(y + (size_t)node * 8);
        float4 a = yp[0], b = yp[1];
        ya[mt][0] = a.x; ya[mt][1] = a.y; ya[mt][2] = a.z; ya[mt][3] = a.w;
        ya[mt][4] = b.x; ya[mt][5] = b.y; ya[mt][6] = b.z; ya[mt][7] = b.w;
    }

    f32x4 acc[2][8];
    #pragma unroll
    for (int mt = 0; mt < 2; ++mt)
        #pragma unroll
        for (int f = 0; f < 8; ++f)
            acc[mt][f] = (f32x4){0.f, 0.f, 0.f, 0.f};

    auto stage = [&](int b, int cc) {
        const char* src = (const char*)(Wswz + (size_t)cc * 8192);
        #pragma unroll
        for (int i = 0; i < 4; ++i) {
            int off = (i * 256 + tid) * 16;
            GLDS16(src + off, (char*)Wb[b] + off);
        }
        int nl = tid >> 1, c4 = (tid & 1) * 4;
        int node = n0 + nl;
        if (node >= N) node = N - 1;
        GLDS16(x + (size_t)node * 128 + cc * 8 + c4, (char*)xs[b] + tid * 16);
    };

    stage(0, 0);
    __syncthreads();

    for (int cc = 0; cc < 16; ++cc) {
        int cur = cc & 1;
        if (cc < 15) stage(cur ^ 1, cc + 1);

        #pragma unroll
        for (int ks = 0; ks < 2; ++ks) {
            short8 bfr[8];
            #pragma unroll
            for (int f = 0; f < 8; ++f)
                bfr[f] = *(const short8*)((const short*)Wb[cur] +
                                          (size_t)ks * 4096 + (f * 64 + lane) * 8);
            #pragma unroll
            for (int mt = 0; mt < 2; ++mt) {
                float xv = xs[cur][(wv * 32 + mt * 16 + wl) * 8 + ks * 4 + quad];
                short8 af;
                #pragma unroll
                for (int v = 0; v < 8; ++v) af[v] = f2bf(xv * ya[mt][v]);
                #pragma unroll
                for (int f = 0; f < 8; ++f)
                    acc[mt][f] = __builtin_amdgcn_mfma_f32_16x16x32_bf16(
                        af, bfr[f], acc[mt][f], 0, 0, 0);
            }
        }
        __syncthreads();
    }

    #pragma unroll
    for (int mt = 0; mt < 2; ++mt) {
        #pragma unroll
        for (int r = 0; r < 4; ++r) {
            int node = n0 + wv * 32 + mt * 16 + quad * 4 + r;
            if (node < N) {
                #pragma unroll
                for (int f = 0; f < 8; ++f)
                    out[(size_t)node * 128 + f * 16 + wl] = acc[mt][f][r] * scale;
            }
        }
    }
}

// ---------------------------------------------------------------------------
// Edge kernel over dst-SORTED edge order (via perm). fc1/fc2 as before; the
// epilogue merges runs of equal dst across each quad's 4 consecutive sorted
// edges in-register, flushing one atomic per run: expected 2.67x fewer
// atomic ops (the saturated resource), plus L2-local atomic addresses.
// ---------------------------------------------------------------------------
__global__ __launch_bounds__(256, 4) void edge_mfma_kernel(
    const int* __restrict__ esrc, const int* __restrict__ edst,
    const float* __restrict__ eattr, const float* __restrict__ escal,
    const int* __restrict__ perm,
    const __hip_bfloat16* __restrict__ W1swz,   // 8192  shorts (K=64 swizzled)
    const __hip_bfloat16* __restrict__ W2swz,   // 16384 shorts (K=128 swizzled)
    const float* __restrict__ sf, float* __restrict__ rfeat)
{
    __shared__ __hip_bfloat16 hA[16384];   // 32 KB  A-frag-major hidden

    const int tid = threadIdx.x;
    const int lane = tid & 63;
    const int wv = tid >> 6;
    const int quad = lane >> 4;
    const int wl = lane & 15;
    const int e0 = blockIdx.x * 128;

    // permuted edge id for this lane's A-frag rows (row m = wl)
    int epm[2];
    #pragma unroll
    for (int mt = 0; mt < 2; ++mt) {
        int j = e0 + (wv * 2 + mt) * 16 + wl;
        if (j >= NE) j = NE - 1;
        epm[mt] = perm[j];
    }

    // ---- fc1: [128 x 64] @ [64 x 128] ----
    short8 af1[2][2];
    #pragma unroll
    for (int ks = 0; ks < 2; ++ks)
        #pragma unroll
        for (int mt = 0; mt < 2; ++mt) {
            const float4* p = (const float4*)(escal + (size_t)epm[mt] * 64 +
                                              ks * 32 + quad * 8);
            float4 a = p[0], b = p[1];
            short8 v;
            v[0] = f2bf(a.x); v[1] = f2bf(a.y); v[2] = f2bf(a.z); v[3] = f2bf(a.w);
            v[4] = f2bf(b.x); v[5] = f2bf(b.y); v[6] = f2bf(b.z); v[7] = f2bf(b.w);
            af1[ks][mt] = v;
        }

    f32x4 acc1[2][8];
    #pragma unroll
    for (int mt = 0; mt < 2; ++mt)
        #pragma unroll
        for (int f = 0; f < 8; ++f) acc1[mt][f] = (f32x4){0.f, 0.f, 0.f, 0.f};

    #pragma unroll
    for (int ks = 0; ks < 2; ++ks)
        #pragma unroll
        for (int f = 0; f < 8; ++f) {
            short8 bfr = *(const short8*)((const short*)W1swz +
                                          (size_t)ks * 4096 + (f * 64 + lane) * 8);
            acc1[0][f] = __builtin_amdgcn_mfma_f32_16x16x32_bf16(
                af1[0][0], bfr, acc1[0][f], 0, 0, 0);
            acc1[1][f] = __builtin_amdgcn_mfma_f32_16x16x32_bf16(
                af1[0][1], bfr, acc1[1][f], 0, 0, 0);
            // note: ks handled via af1[ks][mt]; keep explicit below
        }

    // redo properly: the loop above must use af1[ks][*]; rewritten explicitly:
    #pragma unroll
    for (int mt = 0; mt < 2; ++mt)
        #pragma unroll
        for (int f = 0; f < 8; ++f) acc1[mt][f] = (f32x4){0.f, 0.f, 0.f, 0.f};
    #pragma unroll
    for (int ks = 0; ks < 2; ++ks)
        #pragma unroll
        for (int f = 0; f < 8; ++f) {
            short8 bfr = *(const short8*)((const short*)W1swz +
                                          (size_t)ks * 4096 + (f * 64 + lane) * 8);
            acc1[0][f] = __builtin_amdgcn_mfma_f32_16x16x32_bf16(
                af1[ks][0], bfr, acc1[0][f], 0, 0, 0);
            acc1[1][f] = __builtin_amdgcn_mfma_f32_16x16x32_bf16(
                af1[ks][1], bfr, acc1[1][f], 0, 0, 0);
        }

    // silu + write h to hA in fc2 A-frag order
    #pragma unroll
    for (int mt = 0; mt < 2; ++mt) {
        int MT = wv * 2 + mt;
        #pragma unroll
        for (int f = 0; f < 8; ++f) {
            int s2 = f >> 1;
            int q2 = ((f & 1) * 2 + (wl >> 3)) & 3;
            int j2 = wl & 7;
            #pragma unroll
            for (int r = 0; r < 4; ++r) {
                float t = acc1[mt][f][r] * 0.125f;              // 1/sqrt(64)
                float h = SILU_NORM * t / (1.f + __expf(-t));
                int lpos = q2 * 16 + quad * 4 + r;
                ((short*)hA)[((size_t)(s2 * 8 + MT) * 64 + lpos) * 8 + j2] = f2bf(h);
            }
        }
    }
    __syncthreads();

    // ---- fc2: [128 x 128] @ [128 x 128] ----
    f32x4 acc2[2][8];
    #pragma unroll
    for (int mt = 0; mt < 2; ++mt)
        #pragma unroll
        for (int f = 0; f < 8; ++f) acc2[mt][f] = (f32x4){0.f, 0.f, 0.f, 0.f};

    #pragma unroll
    for (int ks = 0; ks < 4; ++ks) {
        short8 afA = *(const short8*)((const short*)hA +
                                      ((size_t)(ks * 8 + wv * 2 + 0) * 64 + lane) * 8);
        short8 afB = *(const short8*)((const short*)hA +
                                      ((size_t)(ks * 8 + wv * 2 + 1) * 64 + lane) * 8);
        #pragma unroll
        for (int f = 0; f < 8; ++f) {
            short8 bfr = *(const short8*)((const short*)W2swz +
                                          (size_t)ks * 4096 + (f * 64 + lane) * 8);
            acc2[0][f] = __builtin_amdgcn_mfma_f32_16x16x32_bf16(
                afA, bfr, acc2[0][f], 0, 0, 0);
            acc2[1][f] = __builtin_amdgcn_mfma_f32_16x16x32_bf16(
                afB, bfr, acc2[1][f], 0, 0, 0);
        }
    }

    // epilogue: sorted-run merge, then atomicAdd per distinct dst in the run.
    const float s128 = 0.08838834764831845f;   // 1/sqrt(128)
    #pragma unroll
    for (int mt = 0; mt < 2; ++mt) {
        int jbase = e0 + (wv * 2 + mt) * 16 + quad * 4;
        if (jbase < NE) {   // NE%4==0 -> whole quad-group valid
            int4 pj = *(const int4*)(perm + jbase);
            int dsts[4], srcs[4];
            float eas[4];
            #pragma unroll
            for (int r = 0; r < 4; ++r) {
                int e = (r == 0) ? pj.x : (r == 1) ? pj.y : (r == 2) ? pj.z : pj.w;
                dsts[r] = edst[e];
                srcs[r] = esrc[e];
                eas[r]  = eattr[e] * s128;
            }
            float run[8];
            int curdst = dsts[0];
            #pragma unroll
            for (int f = 0; f < 8; ++f)
                run[f] = acc2[mt][f][0] * eas[0] *
                         sf[(size_t)srcs[0] * 128 + f * 16 + wl];
            #pragma unroll
            for (int r = 1; r < 4; ++r) {
                float val[8];
                #pragma unroll
                for (int f = 0; f < 8; ++f)
                    val[f] = acc2[mt][f][r] * eas[r] *
                             sf[(size_t)srcs[r] * 128 + f * 16 + wl];
                if (dsts[r] == curdst) {
                    #pragma unroll
                    for (int f = 0; f < 8; ++f) run[f] += val[f];
                } else {
                    #pragma unroll
                    for (int f = 0; f < 8; ++f)
                        atomicAdd(&rfeat[(size_t)curdst * 128 + f * 16 + wl], run[f]);
                    curdst = dsts[r];
                    #pragma unroll
                    for (int f = 0; f < 8; ++f) run[f] = val[f];
                }
            }
            #pragma unroll
            for (int f = 0; f < 8; ++f)
                atomicAdd(&rfeat[(size_t)curdst * 128 + f * 16 + wl], run[f]);
        }
    }
}

// ---------------------------------------------------------------------------
// Fused tail: conv = fctp(rfeat, rattr, W_lin2), angle from the same f32
// A-products, out = cos(a)*rsc + sin(a)*conv. 2-phase double-buffered K-loop.
// ---------------------------------------------------------------------------
__global__ __launch_bounds__(256) void conv_fuse_kernel(
    const float* __restrict__ x, const float* __restrict__ y,
    const __hip_bfloat16* __restrict__ Wswz, const float* __restrict__ W3,
    const float* __restrict__ rsc, float* __restrict__ out, int N)
{
    __shared__ __hip_bfloat16 Wb[2][8192];  // 32 KB
    __shared__ float xs[2][128 * 8];        // 8 KB

    const int tid = threadIdx.x;
    const int lane = tid & 63;
    const int wv = tid >> 6;
    const int quad = lane >> 4;
    const int wl = lane & 15;
    const int n0 = blockIdx.x * 128;

    float ya[2][8];
    #pragma unroll
    for (int mt = 0; mt < 2; ++mt) {
        int node = n0 + wv * 32 + mt * 16 + wl;
        if (node >= N) node = N - 1;
        const float4* yp = (const float4*)(y + (size_t)node * 8);
        float4 a = yp[0], b = yp[1];
        ya[mt][0] = a.x; ya[mt][1] = a.y; ya[mt][2] = a.z; ya[mt][3] = a.w;
        ya[mt][4] = b.x; ya[mt][5] = b.y; ya[mt][6] = b.z; ya[mt][7] = b.w;
    }

    f32x4 acc[2][8];
    #pragma unroll
    for (int mt = 0; mt < 2; ++mt)
        #pragma unroll
        for (int f = 0; f < 8; ++f)
            acc[mt][f] = (f32x4){0.f, 0.f, 0.f, 0.f};
    float aacc[2] = {0.f, 0.f};

    auto stage = [&](int b, int cc) {
        const char* src = (const char*)(Wswz + (size_t)cc * 8192);
        #pragma unroll
        for (int i = 0; i < 4; ++i) {
            int off = (i * 256 + tid) * 16;
            GLDS16(src + off, (char*)Wb[b] + off);
        }
        int nl = tid >> 1, c4 = (tid & 1) * 4;
        int node = n0 + nl;
        if (node >= N) node = N - 1;
        GLDS16(x + (size_t)node * 128 + cc * 8 + c4, (char*)xs[b] + tid * 16);
    };

    stage(0, 0);
    __syncthreads();

    for (int cc = 0; cc < 16; ++cc) {
        int cur = cc & 1;
        if (cc < 15) stage(cur ^ 1, cc + 1);

        #pragma unroll
        for (int ks = 0; ks < 2; ++ks) {
            short8 bfr[8];
            #pragma unroll
            for (int f = 0; f < 8; ++f)
                bfr[f] = *(const short8*)((const short*)Wb[cur] +
                                          (size_t)ks * 4096 + (f * 64 + lane) * 8);
            const float4* wp = (const float4*)(W3 + ((cc * 8 + ks * 4 + quad) * 8));
            float4 w3a = wp[0], w3b = wp[1];
            float w3v[8] = {w3a.x, w3a.y, w3a.z, w3a.w, w3b.x, w3b.y, w3b.z, w3b.w};
            #pragma unroll
            for (int mt = 0; mt < 2; ++mt) {
                float xv = xs[cur][(wv * 32 + mt * 16 + wl) * 8 + ks * 4 + quad];
                short8 af;
                #pragma unroll
                for (int v = 0; v < 8; ++v) {
                    float pr = xv * ya[mt][v];
                    af[v] = f2bf(pr);
                    aacc[mt] += pr * w3v[v];
                }
                #pragma unroll
                for (int f = 0; f < 8; ++f)
                    acc[mt][f] = __builtin_amdgcn_mfma_f32_16x16x32_bf16(
                        af, bfr[f], acc[mt][f], 0, 0, 0);
            }
        }
        __syncthreads();
    }

    float ared[2];
    #pragma unroll
    for (int mt = 0; mt < 2; ++mt) {
        float a = aacc[mt];
        a += __shfl_xor(a, 16);
        a += __shfl_xor(a, 32);
        ared[mt] = a * 5.524271728019903e-4f;   // 0.1/(32*sqrt(32))
    }

    const float cs = 5.524271728019903e-3f;     // 1/(32*sqrt(32))
    #pragma unroll
    for (int mt = 0; mt < 2; ++mt) {
        #pragma unroll
        for (int r = 0; r < 4; ++r) {
            int node = n0 + wv * 32 + mt * 16 + quad * 4 + r;
            float a = __shfl(ared[mt], quad * 4 + r);
            if (node < N) {
                float ca = __cosf(a), sa = __sinf(a);
                #pragma unroll
                for (int f = 0; f < 8; ++f) {
                    size_t o = (size_t)node * 128 + f * 16 + wl;
                    out[o] = ca * rsc[o] + sa * (acc[mt][f][r] * cs);
                }
            }
        }
    }
}

// ---------------------------------------------------------------------------
extern "C" void kernel_launch(void* const* d_in, const int* in_sizes, int n_in,
                              void* d_out, int out_size, void* d_ws, size_t ws_size,
                              hipStream_t stream)
{
    const float* sender_input   = (const float*)d_in[0];
    const float* sender_attr    = (const float*)d_in[1];
    const float* receiver_input = (const float*)d_in[2];
    const float* receiver_attr  = (const float*)d_in[3];
    const int*   edge_src  = (const int*)d_in[4];
    const int*   edge_dst  = (const int*)d_in[5];
    const float* edge_attr = (const float*)d_in[6];
    const float* edge_scal = (const float*)d_in[7];
    const float* W_sc   = (const float*)d_in[8];
    const float* W_lin1 = (const float*)d_in[9];
    const float* W_fc1  = (const float*)d_in[10];
    const float* W_fc2  = (const float*)d_in[11];
    const float* W_lin2 = (const float*)d_in[12];
    const float* W_lin3 = (const float*)d_in[13];

    char* ws = (char*)d_ws;
    float* sf    = (float*)(ws);               // 51.2 MB ; reused as rsc after edge kernel
    float* rfeat = (float*)(ws + 51200000);    // 51.2 MB
    __hip_bfloat16* Wl1s = (__hip_bfloat16*)(ws + 102400000);  // 262144 B
    __hip_bfloat16* Wscs = (__hip_bfloat16*)(ws + 102662144);  // 262144 B
    __hip_bfloat16* Wl2s = (__hip_bfloat16*)(ws + 102924288);  // 262144 B
    __hip_bfloat16* W1s  = (__hip_bfloat16*)(ws + 103186432);  // 16384 B
    __hip_bfloat16* W2s  = (__hip_bfloat16*)(ws + 103202816);  // 32768 B
    float* rsc = sf;

    // sort scratch lives in d_out (unused until conv_fuse overwrites it)
    int* perm = (int*)d_out;            // NE ints
    int* cnt  = (int*)d_out + 600000;   // NR ints
    int* ofs  = (int*)d_out + 700000;   // NR ints
    int* bsum = (int*)d_out + 800000;   // <=128 ints
    int* bofs = (int*)d_out + 800128;

    // weight pre-swizzles (one-time per launch, tiny)
    swz_kernel<<<512, 256, 0, stream>>>(W_lin1, Wl1s, 131072);
    swz_kernel<<<512, 256, 0, stream>>>(W_sc,   Wscs, 131072);
    swz_kernel<<<512, 256, 0, stream>>>(W_lin2, Wl2s, 131072);
    swz_kernel<<<32,  256, 0, stream>>>(W_fc1,  W1s,  8192);
    swz_kernel<<<64,  256, 0, stream>>>(W_fc2,  W2s,  16384);

    hipMemsetAsync(rfeat, 0, (size_t)NR * 128 * 4, stream);
    hipMemsetAsync(cnt, 0, (size_t)NR * 4, stream);

    // counting sort of edges by dst
    const int nbScan = (NR + SCAN_BLK - 1) / SCAN_BLK;   // 98
    hist_kernel<<<(NE + 255) / 256, 256, 0, stream>>>(edge_dst, cnt);
    scan1_kernel<<<nbScan, 256, 0, stream>>>(cnt, bsum, NR);
    scan2_kernel<<<1, 128, 0, stream>>>(bsum, bofs, nbScan);
    scan3_kernel<<<nbScan, 256, 0, stream>>>(cnt, bofs, ofs, NR);
    scatter_kernel<<<(NE + 255) / 256, 256, 0, stream>>>(edge_dst, ofs, perm);

    // sender_features = fctp(sender_input, sender_attr, W_lin1), scale 1/32
    fctp_mfma_kernel<<<(NS + 127) / 128, 256, 0, stream>>>(
        sender_input, sender_attr, Wl1s, sf, 0.03125f, NS);
    // edge FC + gather + sorted-merged scatter
    edge_mfma_kernel<<<(NE + 127) / 128, 256, 0, stream>>>(
        edge_src, edge_dst, edge_attr, edge_scal, perm, W1s, W2s, sf, rfeat);
    // rsc = fctp(receiver_input, rattr, W_sc) * 1/32  (overwrites sf slot)
    fctp_mfma_kernel<<<(NR + 127) / 128, 256, 0, stream>>>(
        receiver_input, receiver_attr, Wscs, rsc, 0.03125f, NR);
    // fused conv + angle + trig combine -> out
    conv_fuse_kernel<<<(NR + 127) / 128, 256, 0, stream>>>(
        rfeat, receiver_attr, Wl2s, W_lin3, rsc, (float*)d_out, NR);
}